// Round 2
// baseline (111.514 us; speedup 1.0000x reference)
//
#include <hip/hip_runtime.h>
#include <math.h>

// ShadowMapping forward: hard + soft shadow maps.
// R19 = R18 + 2 pixels/thread (4 pixel-lights) for 2x memory-level parallelism.
//   Post-mortem R18: rowquad merge + phase batching -> fused ~48 -> ~40us.
//   Remaining cost model: TA lane-request serialization (~14us) + L2 line BW
//   (~16us) + UNHIDDEN LATENCY (occupancy 40%, 3.2 waves/SIMD, one 6-gather
//   batch per wave). R19 doubles in-flight gathers per wave (12) WITHOUT
//   growing per-XCD L2 footprint (same id&7 light-pair XCD affinity).
//   Also: 8B-aligned rowquad base ((u-1)&~1) cuts dwordx4 line straddle
//   19%->12%; __launch_bounds__(128,4) lets allocator keep the batch in regs
//   (R16 failure mode: VGPR capped at 28, batch re-sunk).
//   Tap values and FLOP accumulation order bit-identical to R18.
//   Validated chain: geometry fmuladd (R2), 3x3->plus blur (R6/R9), poly-sin
//   (R7), setup offload (R11), mask gating + threshold (R13), rowquad
//   dwordx4 + phase A/B split + sched_barrier pin (R18).

#define RESN 512
#define NL 16
#define NPIX (RESN*RESN)

typedef float f4a __attribute__((ext_vector_type(4), aligned(4)));
typedef float f2a __attribute__((ext_vector_type(2), aligned(8)));

__global__ void setup_kernel(const float* __restrict__ als,
                             float* __restrict__ lp) {
  #pragma clang fp contract(off)
  int l = (int)threadIdx.x;
  if (l >= NL) return;
  float xd = als[l*7+0], yd = als[l*7+1], zd = als[l*7+2], sg = als[l*7+3];
  float cosp = sqrtf(xd*xd + zd*zd);
  float cost = zd / cosp;
  float sint = xd / cosp;
  float* o = lp + l*16;
  o[0] = cost;               // e00
  o[1] = -sint;              // e02
  o[2] = (-sint)*yd;         // e10
  o[3] = cosp;               // e11
  o[4] = (-cost)*yd;         // e12
  o[5] = cosp*sint;          // e20
  o[6] = yd;                 // e21
  o[7] = cosp*cost;          // e22
  // radius-1 Gaussian, normalized over the full 21-tap sum (validated R6)
  float sig = ((2.0f*(6.0f*sg + 1.0f)) - 1.0f) / 6.0f;
  float ivs = 1.0f/(sig*sig);
  float e1  = __builtin_amdgcn_exp2f(-0.72134752044448170368f*ivs);
  float e1sq = e1*e1;
  float e2  = e1sq*e1sq;
  float kinv = 1.0f/(1.0f + 2.0f*e1 + 2.0f*e2);
  float w1n = e1*kinv;
  o[8] = kinv;               // w0
  o[9] = w1n;                // w1
  // side-tap worst-case sf delta = (2/pi)*w0*4*w1n*0.93 <= 0.0115 at cutoff
  o[10] = (w1n >= 0.0056f) ? 1.0f : 0.0f;      // 5-tap mode flag
  o[11] = kinv*kinv;         // w0^2 (1-tap path)
  o[12] = o[13] = o[14] = o[15] = 0.0f;
}

__global__ __launch_bounds__(128, 4) void fused_kernel(
    const float* __restrict__ depth,
    const float* __restrict__ mask,
    const float* __restrict__ z_map,
    const float* __restrict__ lp,
    float* __restrict__ out,
    float TANHF, float OZF, float OWF)
{
  #pragma clang fp contract(off)
  const float OFFS = -0.0642233295781f;
  const float CLB  = 0.4458709375254f;
  const float TWO_OVER_PI = 0.63661977236758134308f;
  // 8192 blocks: id&7 = light pair (l, l+8) — XCD affinity (2MB z per XCD);
  // id>>3 in [0,1024) = 256-px chunk (half row); thread t owns pixels
  // p0 = chunk*256 + 2t and p0+1 (same row, adjacent columns).
  const int id = (int)blockIdx.x;
  const int l0 = id & 7;
  const int p0 = ((id >> 3) << 8) + ((int)threadIdx.x << 1);
  const int r  = p0 >> 9, c0 = p0 & 511;

  f2a dzv = *reinterpret_cast<const f2a*>(depth + p0);
  f2a mkv = *reinterpret_cast<const f2a*>(mask + p0);
  float m1r = 2.0f * ((float)r / 512.0f + 0.0009765625f) - 1.0f;
  float qx[2], qy[2], qz[2];
  #pragma unroll
  for (int j = 0; j < 2; ++j) {
    float m1c = 2.0f * ((float)(c0 + j) / 512.0f + 0.0009765625f) - 1.0f;
    float tT = dzv[j] * TANHF;
    qx[j] = tT * m1c;
    qy[j] = tT * m1r;
    qz[j] = 2.7f - dzv[j];
  }

  float hard[2][2] = {{0.0f,0.0f},{0.0f,0.0f}};
  float soft[2][2] = {{0.0f,0.0f},{0.0f,0.0f}};

  // ---- phase A: geometry + ALL gather issue (2 lights x 2 pixels) ----
  float rx_[2][2] = {}, ry_[2][2] = {}, rz_[2][2] = {}, rw_[2][2] = {};
  float zT_[2][2] = {}, zB_[2][2] = {};
  float wvT_[2][2] = {}, wvB_[2][2] = {};
  float dd_[2][2] = {};
  int   u_[2][2] = {}, ic_[2][2] = {{1,1},{1,1}};
  float w0_[2], w1_[2], w0q_[2];
  bool  ft_[2];

  #pragma unroll
  for (int k = 0; k < 2; ++k) {
    const int l = l0 + (k << 3);
    const int base = l << 18;
    const float* P = lp + l*16;       // block-uniform -> scalar loads
    float e00 = P[0], e02 = P[1], e10 = P[2], e11 = P[3], e12 = P[4];
    float e20 = P[5], e21 = P[6], e22 = P[7];
    w0_[k] = P[8]; w1_[k] = P[9]; w0q_[k] = P[11];
    const bool ft = P[10] != 0.0f;
    ft_[k] = ft;

    #pragma unroll
    for (int j = 0; j < 2; ++j) {
      if (mkv[j] != 0.0f) {
        // XLA dot emitter: sequential fmuladd over w (validated R2)
        float X1 = fmaf(qz[j], e02, qx[j] * e00);
        float Y1 = fmaf(qz[j], e12, fmaf(qy[j], e11, qx[j] * e10));
        float T2 = fmaf(qz[j], e22, fmaf(qy[j], e21, qx[j] * e20));
        float Z1 = T2 + (-2.7f);
        float ZZ = (Z1 * OZF) + OWF;
        float uf = (X1 + 1.0f) * 256.0f;
        float vf = (Y1 + 1.0f) * 256.0f;
        int u = (int)uf; u = u < 0 ? 0 : (u > 511 ? 511 : u);
        int v = (int)vf; v = v < 0 ? 0 : (v > 511 ? 511 : v);
        float dd = 0.5f * (1.0f + ZZ);
        dd = fminf(fmaxf(dd, 0.0f), 1.0f);
        dd_[k][j] = dd;
        u_[k][j] = u;

        const float* zrC = z_map + base + (v << 9);
        if (ft) {
          // one dwordx4 covers taps u-1,u,u+1; 8B-aligned base cuts
          // 64B-line straddle to 12.5%
          int b = (u - 1) & ~1;
          b = b < 0 ? 0 : (b > 508 ? 508 : b);
          f4a rv = *reinterpret_cast<const f4a*>(zrC + b);
          rx_[k][j] = rv.x; ry_[k][j] = rv.y;
          rz_[k][j] = rv.z; rw_[k][j] = rv.w;
          ic_[k][j] = u - b;             // 0..3
          int v0 = v > 0 ? v - 1 : 0;
          int v2 = v < 511 ? v + 1 : 511;
          zT_[k][j] = z_map[base + (v0 << 9) + u];
          zB_[k][j] = z_map[base + (v2 << 9) + u];
          wvT_[k][j] = (v > 0)   ? w1_[k] : 0.0f;
          wvB_[k][j] = (v < 511) ? w1_[k] : 0.0f;
        } else {
          ry_[k][j] = zrC[u];            // center only (1-tap mode)
          ic_[k][j] = 1;
        }
      }
    }
  }

  // Pin VMEM above the compute phase (ALU/SALU may cross to fill gaps).
  // mask 0x7 = ALU|VALU|SALU may cross; VMEM/DS may NOT.
  __builtin_amdgcn_sched_barrier(0x7);

  // ---- phase B: fval + blend (2 lights x 2 pixels) ----
  #pragma unroll
  for (int k = 0; k < 2; ++k) {
    const float w0 = w0_[k], w1 = w1_[k];
    #pragma unroll
    for (int j = 0; j < 2; ++j) {
      if (mkv[j] != 0.0f) {
        const float dpo = dd_[k][j] + OFFS;
        // f = sum_{m odd<=7} (1/m) sin(m*pi*(z-dpo)) = s*P(s^2)
        auto fval = [&](float z) {
          float s = __builtin_amdgcn_sinf(0.5f * (z - dpo));   // revolutions
          float t = s * s;
          return s * fmaf(t, fmaf(t, fmaf(t, -9.142857142857142f, 19.2f),
                                  -13.333333333333334f), 4.0f);
        };
        float q, zg;
        if (ft_[k]) {
          // resolve edge-clamped quad indices (ic in {1,2} common case)
          bool e0 = ic_[k][j] == 0, e2 = ic_[k][j] == 2, e3 = ic_[k][j] == 3;
          float zC = e0 ? rx_[k][j] : e2 ? rz_[k][j] : e3 ? rw_[k][j] : ry_[k][j];
          float zL = e0 ? rx_[k][j] : e2 ? ry_[k][j] : e3 ? rz_[k][j] : rx_[k][j];
          float zR = e0 ? ry_[k][j] : (e2 | e3) ? rw_[k][j] : rz_[k][j];
          int u = u_[k][j];
          float wuL = (u > 0)   ? w1 : 0.0f;
          float wuR = (u < 511) ? w1 : 0.0f;
          // same accumulation order as R17/R18 (bit-compat): C, T, B, L, R
          float qs = w0 * fval(zC);
          qs = fmaf(wvT_[k][j], fval(zT_[k][j]), qs);
          qs = fmaf(wvB_[k][j], fval(zB_[k][j]), qs);
          qs = fmaf(wuL, fval(zL), qs);
          qs = fmaf(wuR, fval(zR), qs);
          q = TWO_OVER_PI * (w0 * qs);
          zg = zC;
        } else {
          // 1-tap mode: side weights < 5.6e-3 dropped (validated R13)
          zg = ry_[k][j];
          q = TWO_OVER_PI * (w0q_[k] * fval(zg));
        }
        float diff = fmaxf(dd_[k][j] - zg, 0.0f);
        hard[k][j] = mkv[j] * ((diff > 0.008f) ? 0.0f : 1.0f);
        float qc = fminf(fmaxf(q, -CLB), CLB) / CLB;
        float sf = 0.5f * (qc + 1.0f);
        soft[k][j] = mkv[j] * fminf(fmaxf(sf, 0.0f), 1.0f);
      }
    }
  }

  #pragma unroll
  for (int k = 0; k < 2; ++k) {
    const int base = (l0 + (k << 3)) << 18;
    f2a h; h.x = hard[k][0]; h.y = hard[k][1];
    f2a s; s.x = soft[k][0]; s.y = soft[k][1];
    *reinterpret_cast<f2a*>(out + base + p0) = h;
    *reinterpret_cast<f2a*>(out + (NL*NPIX) + base + p0) = s;
  }
}

extern "C" void kernel_launch(void* const* d_in, const int* in_sizes, int n_in,
                              void* d_out, int out_size, void* d_ws, size_t ws_size,
                              hipStream_t stream) {
  (void)in_sizes; (void)n_in; (void)out_size; (void)ws_size;
  const float* depth = (const float*)d_in[0];
  const float* als   = (const float*)d_in[1];
  const float* mask  = (const float*)d_in[2];
  const float* z_map = (const float*)d_in[3];
  float* out = (float*)d_out;
  float* lp = (float*)d_ws;                       // 16 lights x 16 floats = 1KB
  // constants in double, replicating numpy, then rounded to f32
  double TANH = tan(2.0*atan(0.5*36.0/50.0)/2.0);
  double NEARc = 2.7 - sqrt(2.0)*2.7*TANH;
  double FARc  = 2.7 + sqrt(2.0)*2.7*TANH;
  float ozf = (float)(-2.0/(FARc-NEARc));
  float owf = (float)((-(FARc+NEARc))/(FARc-NEARc));
  float tanhf_ = (float)TANH;

  setup_kernel<<<1, 64, 0, stream>>>(als, lp);
  fused_kernel<<<(NL/2)*NPIX/(128*2), 128, 0, stream>>>(depth, mask, z_map, lp,
                                                        out, tanhf_, ozf, owf);
}

// Round 3
// 102.119 us; speedup vs baseline: 1.0920x; 1.0920x over previous
//
#include <hip/hip_runtime.h>
#include <math.h>

// ShadowMapping forward: hard + soft shadow maps.
// R20 = R18 revert (1 px/thread) + XCD load-BALANCING via temporal phasing.
//   Post-mortem R19: 2px/thread regressed total (+5.7us) — per-wave MLP was
//   not the binding constraint. New theory: only ~30% of lights are 5-tap
//   (w1n>=0.0056 needs sigma>~0.089; sigma~U[0.02,0.12]), so the old
//   l0 = id&7 mapping PINNED each light pair to one XCD (id&7 period == 8
//   XCD round-robin) -> XCDs owning 5-tap pairs do ~3x the scattered-gather
//   work; slowest XCD sets kernel time (~41us vs ~22us balanced estimate).
//   Fix: l0 = id>>11 (high bits) — each pair becomes a 2048-block phase
//   spread across ALL XCDs; per-XCD L2 footprint still ~2MB/pair at any
//   instant (L3 backstops phase transitions); work balanced across XCDs.
//   Also kept from R19 (mechanism sound, bit-compat): 8B-aligned rowquad
//   base (u-1)&~1 cuts dwordx4 64B-line straddle 19%->12%.
//   Tap values and FLOP accumulation order bit-identical to R17/R18.
//   Validated chain: geometry fmuladd (R2), 3x3->plus blur (R6/R9), poly-sin
//   (R7), setup offload (R11), mask gating + threshold (R13), rowquad
//   dwordx4 + phase A/B split + sched_barrier pin (R18).

#define RESN 512
#define NL 16
#define NPIX (RESN*RESN)

typedef float f4a __attribute__((ext_vector_type(4), aligned(4)));

__global__ void setup_kernel(const float* __restrict__ als,
                             float* __restrict__ lp) {
  #pragma clang fp contract(off)
  int l = (int)threadIdx.x;
  if (l >= NL) return;
  float xd = als[l*7+0], yd = als[l*7+1], zd = als[l*7+2], sg = als[l*7+3];
  float cosp = sqrtf(xd*xd + zd*zd);
  float cost = zd / cosp;
  float sint = xd / cosp;
  float* o = lp + l*16;
  o[0] = cost;               // e00
  o[1] = -sint;              // e02
  o[2] = (-sint)*yd;         // e10
  o[3] = cosp;               // e11
  o[4] = (-cost)*yd;         // e12
  o[5] = cosp*sint;          // e20
  o[6] = yd;                 // e21
  o[7] = cosp*cost;          // e22
  // radius-1 Gaussian, normalized over the full 21-tap sum (validated R6)
  float sig = ((2.0f*(6.0f*sg + 1.0f)) - 1.0f) / 6.0f;
  float ivs = 1.0f/(sig*sig);
  float e1  = __builtin_amdgcn_exp2f(-0.72134752044448170368f*ivs);
  float e1sq = e1*e1;
  float e2  = e1sq*e1sq;
  float kinv = 1.0f/(1.0f + 2.0f*e1 + 2.0f*e2);
  float w1n = e1*kinv;
  o[8] = kinv;               // w0
  o[9] = w1n;                // w1
  // side-tap worst-case sf delta = (2/pi)*w0*4*w1n*0.93 <= 0.0115 at cutoff
  o[10] = (w1n >= 0.0056f) ? 1.0f : 0.0f;      // 5-tap mode flag
  o[11] = kinv*kinv;         // w0^2 (1-tap path)
  o[12] = o[13] = o[14] = o[15] = 0.0f;
}

__global__ __launch_bounds__(128) void fused_kernel(
    const float* __restrict__ depth,
    const float* __restrict__ mask,
    const float* __restrict__ z_map,
    const float* __restrict__ lp,
    float* __restrict__ out,
    float TANHF, float OZF, float OWF)
{
  #pragma clang fp contract(off)
  const float OFFS = -0.0642233295781f;
  const float CLB  = 0.4458709375254f;
  const float TWO_OVER_PI = 0.63661977236758134308f;
  // 16384 blocks: id>>11 = light pair (l, l+8) — contiguous 2048-block
  // phase spreads over all 8 XCDs (load-balanced, ~2MB L2/XCD per phase);
  // id&2047 = 128-px block (quarter row).
  const int id = (int)blockIdx.x;
  const int l0 = id >> 11;
  const int p  = ((id & 2047) << 7) + (int)threadIdx.x;
  const int r  = p >> 9, c = p & 511;

  float dz = depth[p];
  float mk = mask[p];
  float m1c = 2.0f * ((float)c / 512.0f + 0.0009765625f) - 1.0f;
  float m1r = 2.0f * ((float)r / 512.0f + 0.0009765625f) - 1.0f;
  float tT = dz * TANHF;
  float qx = tT * m1c;
  float qy = tT * m1r;
  float qz = 2.7f - dz;
  const bool live = (mk != 0.0f);

  float hard_out[2] = {0.0f, 0.0f};
  float soft_out[2] = {0.0f, 0.0f};

  if (live) {
    // ---- phase A: geometry + ALL gather issue for BOTH lights ----
    float rx[2], ry[2], rz[2], rw[2];   // row quad (covers u-1,u,u+1) or zg
    float zT[2], zB[2];
    float wvT_[2], wvB_[2];             // v-edge-masked side weights
    float dd_[2], dpo_[2];
    float w0_[2], w1_[2], w0q_[2];
    int   u_[2], ic_[2];
    bool  ft_[2];

    #pragma unroll
    for (int k = 0; k < 2; ++k) {
      const int l = l0 + (k << 3);
      const int base = l << 18;
      const float* P = lp + l*16;       // block-uniform -> scalar loads
      float e00 = P[0], e02 = P[1], e10 = P[2], e11 = P[3], e12 = P[4];
      float e20 = P[5], e21 = P[6], e22 = P[7];
      w0_[k] = P[8]; w1_[k] = P[9]; w0q_[k] = P[11];
      bool ft = P[10] != 0.0f;
      ft_[k] = ft;

      // XLA dot emitter: sequential fmuladd over w (validated R2)
      float X1 = fmaf(qz, e02, qx * e00);
      float Y1 = fmaf(qz, e12, fmaf(qy, e11, qx * e10));
      float T2 = fmaf(qz, e22, fmaf(qy, e21, qx * e20));
      float Z1 = T2 + (-2.7f);
      float ZZ = (Z1 * OZF) + OWF;
      float uf = (X1 + 1.0f) * 256.0f;
      float vf = (Y1 + 1.0f) * 256.0f;
      int u = (int)uf; u = u < 0 ? 0 : (u > 511 ? 511 : u);
      int v = (int)vf; v = v < 0 ? 0 : (v > 511 ? 511 : v);
      float dd = 0.5f * (1.0f + ZZ);
      dd = fminf(fmaxf(dd, 0.0f), 1.0f);
      dd_[k] = dd; dpo_[k] = dd + OFFS;
      u_[k] = u;

      const float* zrC = z_map + base + (v << 9);
      if (ft) {
        // one dwordx4 covers taps u-1,u,u+1; 8B-aligned base cuts
        // 64B-line straddle to 12.5%
        int b = (u - 1) & ~1;
        b = b < 0 ? 0 : (b > 508 ? 508 : b);
        f4a rv = *reinterpret_cast<const f4a*>(zrC + b);
        rx[k] = rv.x; ry[k] = rv.y; rz[k] = rv.z; rw[k] = rv.w;
        ic_[k] = u - b;                  // 0..3 (1 or 2 common case)
        int v0 = v > 0 ? v - 1 : 0;
        int v2 = v < 511 ? v + 1 : 511;
        zT[k] = z_map[base + (v0 << 9) + u];
        zB[k] = z_map[base + (v2 << 9) + u];
        wvT_[k] = (v > 0)   ? w1_[k] : 0.0f;
        wvB_[k] = (v < 511) ? w1_[k] : 0.0f;
      } else {
        ry[k] = zrC[u];                  // center only (1-tap mode)
        ic_[k] = 1;
        wvT_[k] = wvB_[k] = 0.0f;
      }
    }

    // Pin VMEM above the compute phase (ALU/SALU may cross to fill gaps).
    // mask 0x7 = ALU|VALU|SALU may cross; VMEM/DS may NOT.
    __builtin_amdgcn_sched_barrier(0x7);

    // ---- phase B: fval + blend for both lights ----
    #pragma unroll
    for (int k = 0; k < 2; ++k) {
      const float dpo = dpo_[k];
      // f = sum_{m odd<=7} (1/m) sin(m*pi*(z-dpo)) = s*P(s^2)
      auto fval = [&](float z) {
        float s = __builtin_amdgcn_sinf(0.5f * (z - dpo));   // revolutions
        float t = s * s;
        return s * fmaf(t, fmaf(t, fmaf(t, -9.142857142857142f, 19.2f),
                                -13.333333333333334f), 4.0f);
      };
      float w0 = w0_[k], w1 = w1_[k];
      float q, zg;
      if (ft_[k]) {
        // resolve edge-clamped quad indices (ic in {1,2} common case)
        bool e0 = ic_[k] == 0, e2 = ic_[k] == 2, e3 = ic_[k] == 3;
        float zC = e0 ? rx[k] : e2 ? rz[k] : e3 ? rw[k] : ry[k];
        float zL = e0 ? rx[k] : e2 ? ry[k] : e3 ? rz[k] : rx[k];
        float zR = e0 ? ry[k] : (e2 | e3) ? rw[k] : rz[k];
        int u = u_[k];
        float wuL = (u > 0)   ? w1 : 0.0f;
        float wuR = (u < 511) ? w1 : 0.0f;
        // same accumulation order as R17/R18 (bit-compat): C, T, B, L, R
        float qs = w0 * fval(zC);
        qs = fmaf(wvT_[k], fval(zT[k]), qs);
        qs = fmaf(wvB_[k], fval(zB[k]), qs);
        qs = fmaf(wuL, fval(zL), qs);
        qs = fmaf(wuR, fval(zR), qs);
        q = TWO_OVER_PI * (w0 * qs);
        zg = zC;
      } else {
        // 1-tap mode: side weights < 5.6e-3 dropped (validated R13)
        zg = ry[k];
        q = TWO_OVER_PI * (w0q_[k] * fval(zg));
      }
      float diff = fmaxf(dd_[k] - zg, 0.0f);
      hard_out[k] = mk * ((diff > 0.008f) ? 0.0f : 1.0f);
      float qc = fminf(fmaxf(q, -CLB), CLB) / CLB;
      float sf = 0.5f * (qc + 1.0f);
      soft_out[k] = mk * fminf(fmaxf(sf, 0.0f), 1.0f);
    }
  }

  #pragma unroll
  for (int k = 0; k < 2; ++k) {
    const int base = (l0 + (k << 3)) << 18;
    out[base + p] = hard_out[k];
    out[(NL*NPIX) + base + p] = soft_out[k];
  }
}

extern "C" void kernel_launch(void* const* d_in, const int* in_sizes, int n_in,
                              void* d_out, int out_size, void* d_ws, size_t ws_size,
                              hipStream_t stream) {
  (void)in_sizes; (void)n_in; (void)out_size; (void)ws_size;
  const float* depth = (const float*)d_in[0];
  const float* als   = (const float*)d_in[1];
  const float* mask  = (const float*)d_in[2];
  const float* z_map = (const float*)d_in[3];
  float* out = (float*)d_out;
  float* lp = (float*)d_ws;                       // 16 lights x 16 floats = 1KB
  // constants in double, replicating numpy, then rounded to f32
  double TANH = tan(2.0*atan(0.5*36.0/50.0)/2.0);
  double NEARc = 2.7 - sqrt(2.0)*2.7*TANH;
  double FARc  = 2.7 + sqrt(2.0)*2.7*TANH;
  float ozf = (float)(-2.0/(FARc-NEARc));
  float owf = (float)((-(FARc+NEARc))/(FARc-NEARc));
  float tanhf_ = (float)TANH;

  setup_kernel<<<1, 64, 0, stream>>>(als, lp);
  fused_kernel<<<(NL/2)*NPIX/128, 128, 0, stream>>>(depth, mask, z_map, lp,
                                                    out, tanhf_, ozf, owf);
}